// Round 1
// baseline (280.208 us; speedup 1.0000x reference)
//
#include <hip/hip_runtime.h>

#define B_   32
#define D_   256
#define HW_  1024
#define N_   32768
#define K_   1024
#define DHW  (D_ * HW_)   // 262144

// Tiling
#define TM   64    // tokens per block
#define TKC  128   // codes per k-tile
#define DC   32    // d chunk
#define NKT  (K_ / TKC)   // 8
#define NDC  (D_ / DC)    // 8

// ---------------- csq: per-code squared norm ----------------
__global__ __launch_bounds__(256)
void csq_kernel(const float* __restrict__ cb, float* __restrict__ csq) {
    int k = blockIdx.x * 4 + (threadIdx.x >> 6);
    int lane = threadIdx.x & 63;
    const float4 v = *reinterpret_cast<const float4*>(cb + (size_t)k * D_ + lane * 4);
    float s = v.x * v.x + v.y * v.y + v.z * v.z + v.w * v.w;
    #pragma unroll
    for (int off = 32; off >= 1; off >>= 1) s += __shfl_xor(s, off, 64);
    if (lane == 0) csq[k] = s;
}

// ---------------- main fused kernel ----------------
__global__ __launch_bounds__(256)
void vq_main(const float* __restrict__ x, const float* __restrict__ cb,
             const float* __restrict__ csq,
             float* __restrict__ out, float* __restrict__ oidx,
             float* __restrict__ oloss) {
    __shared__ float As[DC][TM];      // 8 KB  [d][token]
    __shared__ float Bs[DC][TKC];     // 16 KB [d][code]
    __shared__ float xsq[TM];
    __shared__ float redv[TM][16];    // 4 KB
    __shared__ int   redk[TM][16];    // 4 KB
    __shared__ int   bestk[TM];

    const int tid = threadIdx.x;
    const int tx = tid & 15, ty = tid >> 4;
    const int n0 = blockIdx.x * TM;
    const int b = n0 >> 10;          // n0 / HW_
    const int hw0 = n0 & (HW_ - 1);
    const float* xb = x + (size_t)b * DHW + hw0;

    // ---- per-token squared norm (xsq) ----
    {
        int j = tid & 63, dg = tid >> 6;
        float s = 0.f;
        const float* p = xb + j + (size_t)(dg * 64) * HW_;
        #pragma unroll 8
        for (int d = 0; d < 64; ++d) { float v = p[(size_t)d * HW_]; s = fmaf(v, v, s); }
        float* scr = &redv[0][0];
        scr[dg * 64 + j] = s;
    }
    __syncthreads();
    if (tid < TM) {
        float* scr = &redv[0][0];
        xsq[tid] = scr[tid] + scr[64 + tid] + scr[128 + tid] + scr[192 + tid];
    }
    __syncthreads();

    float minv[4]; int mink[4];
    #pragma unroll
    for (int i = 0; i < 4; ++i) { minv[i] = 3.4e38f; mink[i] = 0; }

    // staging index helpers
    const int a_dd = tid >> 3;           // 0..31
    const int a_j  = (tid & 7) * 8;      // 0,8,..,56
    const int b_kk = tid >> 1;           // 0..127
    const int b_dp = (tid & 1) * 16;     // 0 or 16

    for (int kt = 0; kt < NKT; ++kt) {
        const int k0 = kt * TKC;
        float acc[4][8];
        #pragma unroll
        for (int i = 0; i < 4; ++i)
            #pragma unroll
            for (int c = 0; c < 8; ++c) acc[i][c] = 0.f;

        for (int dc = 0; dc < NDC; ++dc) {
            const int d0 = dc * DC;
            // prefetch to regs
            const float* pa = xb + (size_t)(d0 + a_dd) * HW_ + a_j;
            float4 va0 = *reinterpret_cast<const float4*>(pa);
            float4 va1 = *reinterpret_cast<const float4*>(pa + 4);
            const float* pb = cb + (size_t)(k0 + b_kk) * D_ + d0 + b_dp;
            float4 vb0 = *reinterpret_cast<const float4*>(pb);
            float4 vb1 = *reinterpret_cast<const float4*>(pb + 4);
            float4 vb2 = *reinterpret_cast<const float4*>(pb + 8);
            float4 vb3 = *reinterpret_cast<const float4*>(pb + 12);

            __syncthreads();   // previous chunk's compute reads done
            *reinterpret_cast<float4*>(&As[a_dd][a_j])     = va0;
            *reinterpret_cast<float4*>(&As[a_dd][a_j + 4]) = va1;
            {
                float bv[16] = { vb0.x, vb0.y, vb0.z, vb0.w,
                                 vb1.x, vb1.y, vb1.z, vb1.w,
                                 vb2.x, vb2.y, vb2.z, vb2.w,
                                 vb3.x, vb3.y, vb3.z, vb3.w };
                #pragma unroll
                for (int i = 0; i < 16; ++i) Bs[b_dp + i][b_kk] = bv[i];
            }
            __syncthreads();

            #pragma unroll 8
            for (int dd = 0; dd < DC; ++dd) {
                float4 a4 = *reinterpret_cast<const float4*>(&As[dd][ty * 4]);
                float4 bA = *reinterpret_cast<const float4*>(&Bs[dd][tx * 8]);
                float4 bB = *reinterpret_cast<const float4*>(&Bs[dd][tx * 8 + 4]);
                float av[4] = { a4.x, a4.y, a4.z, a4.w };
                float bv[8] = { bA.x, bA.y, bA.z, bA.w, bB.x, bB.y, bB.z, bB.w };
                #pragma unroll
                for (int i = 0; i < 4; ++i)
                    #pragma unroll
                    for (int c = 0; c < 8; ++c)
                        acc[i][c] = fmaf(av[i], bv[c], acc[i][c]);
            }
        }

        // k-tile epilogue: distances + running argmin (ascending k keeps first-min)
        #pragma unroll
        for (int c = 0; c < 8; ++c) {
            float cs = csq[k0 + tx * 8 + c];
            #pragma unroll
            for (int i = 0; i < 4; ++i) {
                float dist = fmaf(-2.f, acc[i][c], xsq[ty * 4 + i]) + cs;
                if (dist < minv[i]) { minv[i] = dist; mink[i] = k0 + tx * 8 + c; }
            }
        }
    }

    // ---- cross-thread argmin reduction ----
    #pragma unroll
    for (int i = 0; i < 4; ++i) { redv[ty * 4 + i][tx] = minv[i]; redk[ty * 4 + i][tx] = mink[i]; }
    __syncthreads();
    if (tid < TM) {
        float bv = redv[tid][0]; int bk = redk[tid][0];
        #pragma unroll
        for (int t = 1; t < 16; ++t) {
            float v = redv[tid][t]; int kk = redk[tid][t];
            if (v < bv || (v == bv && kk < bk)) { bv = v; bk = kk; }
        }
        bestk[tid] = bk;
        oidx[n0 + tid] = (float)bk;   // idx output compared as float
    }
    __syncthreads();

    // ---- gather codeword -> out, accumulate loss ----
    {
        const int j = tid & 63, dg = tid >> 6;
        const float* cw = cb + (size_t)bestk[j] * D_;
        float* ob = out + (size_t)b * DHW + hw0 + j;
        const float* xp = xb + j;
        float lsum = 0.f;
        #pragma unroll 4
        for (int d = dg * 64; d < dg * 64 + 64; ++d) {
            float q  = cw[d];
            float xv = xp[(size_t)d * HW_];
            ob[(size_t)d * HW_] = q;
            float df = xv - q;
            lsum = fmaf(df, df, lsum);
        }
        #pragma unroll
        for (int off = 32; off >= 1; off >>= 1) lsum += __shfl_xor(lsum, off, 64);
        if ((tid & 63) == 0) {
            float v = lsum * (1.0f / 8388608.0f);   // / (N_*D_)
            atomicAdd(&oloss[0], v);  // codebook_loss
            atomicAdd(&oloss[1], v);  // commitment_loss (identical forward value)
        }
    }
}

extern "C" void kernel_launch(void* const* d_in, const int* in_sizes, int n_in,
                              void* d_out, int out_size, void* d_ws, size_t ws_size,
                              hipStream_t stream) {
    const float* x  = (const float*)d_in[0];
    const float* cb = (const float*)d_in[1];
    float* out   = (float*)d_out;                       // [B,D,H,W] = 8388608
    float* oidx  = out + (size_t)N_ * D_ / 1;           // actually B*D*H*W
    // out region: B*D*H*W = 8388608 ; idx region: N_ = 32768 ; losses: 2
    oidx = out + 8388608;
    float* oloss = out + 8388608 + 32768;
    float* csq = (float*)d_ws;                          // 4 KB scratch

    hipMemsetAsync(oloss, 0, 2 * sizeof(float), stream);
    csq_kernel<<<K_ / 4, 256, 0, stream>>>(cb, csq);
    vq_main<<<N_ / TM, 256, 0, stream>>>(x, cb, csq, out, oidx, oloss);
}